// Round 1
// baseline (579.106 us; speedup 1.0000x reference)
//
#include <hip/hip_runtime.h>

typedef __bf16 bf16;
typedef __bf16 bf16x8 __attribute__((ext_vector_type(8)));
typedef __bf16 bf16x4 __attribute__((ext_vector_type(4)));
typedef float f32x4 __attribute__((ext_vector_type(4)));

// Problem shapes (fixed by the reference setup_inputs)
constexpr int BB   = 8;     // batch
constexpr int LQ   = 2048;
constexpr int LKV  = 1024;
constexpr int DM   = 1024;  // d_model = H*DK
constexpr int DIMG = 512;   // img_model
constexpr int H    = 16;
constexpr int DK   = 64;

// ---------------- fp32 -> bf16 convert (vectorized) ----------------
__global__ __launch_bounds__(256) void cvt_f32_bf16(const float* __restrict__ in,
                                                    bf16* __restrict__ out, int n4) {
  int i = blockIdx.x * 256 + threadIdx.x;
  if (i < n4) {
    const float4 f = ((const float4*)in)[i];
    bf16x4 o;
    o[0] = (bf16)f.x; o[1] = (bf16)f.y; o[2] = (bf16)f.z; o[3] = (bf16)f.w;
    ((bf16x4*)out)[i] = o;
  }
}

// ------------- W [K,N] fp32 -> WT [N,K] bf16 (tiled transpose) -------------
__global__ __launch_bounds__(256) void transpose_w(const float* __restrict__ W,
                                                   bf16* __restrict__ WT, int K, int N) {
  __shared__ float tile[64][65];
  const int k0 = blockIdx.x * 64, n0 = blockIdx.y * 64;
  const int tx = threadIdx.x & 63, tg = threadIdx.x >> 6;  // 4 row groups
#pragma unroll
  for (int i = 0; i < 16; ++i) {
    int row = tg * 16 + i;
    tile[row][tx] = W[(size_t)(k0 + row) * N + n0 + tx];
  }
  __syncthreads();
#pragma unroll
  for (int i = 0; i < 16; ++i) {
    int nrow = tg * 16 + i;
    WT[(size_t)(n0 + nrow) * K + k0 + tx] = (bf16)tile[tx][nrow];
  }
}

// ------------- C[M,N] = A[M,K] @ Bt[N,K]^T + bias ; MFMA 128x128xBK32 -------------
// A, Bt bf16 row-major. OutT = bf16 (projections) or float (final output).
template <typename OutT>
__global__ __launch_bounds__(256) void gemm_bt(const bf16* __restrict__ A,
                                               const bf16* __restrict__ Bt,
                                               const float* __restrict__ bias,
                                               OutT* __restrict__ C,
                                               int M, int N, int K) {
  constexpr int LDT = 40;  // 32 + 8 pad (keeps 16B alignment, 2-way-max bank aliasing)
  __shared__ __align__(16) bf16 As[128 * LDT];
  __shared__ __align__(16) bf16 Bs[128 * LDT];

  const int tid = threadIdx.x;
  const int lane = tid & 63;
  const int wave = tid >> 6;
  const int bm = blockIdx.x, bn = blockIdx.y;
  const int wm = (wave & 1) * 64, wn = (wave >> 1) * 64;
  const int fm = lane & 15;          // A: m index / B: n index
  const int quad = lane >> 4;
  const int fk8 = quad * 8;          // k offset within 32

  f32x4 acc[4][4];
#pragma unroll
  for (int i = 0; i < 4; ++i)
#pragma unroll
    for (int j = 0; j < 4; ++j) {
      f32x4 z = {0.f, 0.f, 0.f, 0.f};
      acc[i][j] = z;
    }

  const int arow = tid >> 2;        // 0..63
  const int acol = (tid & 3) * 8;   // 0,8,16,24
  const bf16* Ab = A + (size_t)(bm * 128) * K;
  const bf16* Bb = Bt + (size_t)(bn * 128) * K;

  for (int k0 = 0; k0 < K; k0 += 32) {
#pragma unroll
    for (int p = 0; p < 2; ++p) {
      int row = arow + p * 64;
      bf16x8 av = *(const bf16x8*)&Ab[(size_t)row * K + k0 + acol];
      *(bf16x8*)&As[row * LDT + acol] = av;
      bf16x8 bv = *(const bf16x8*)&Bb[(size_t)row * K + k0 + acol];
      *(bf16x8*)&Bs[row * LDT + acol] = bv;
    }
    __syncthreads();
    bf16x8 af[4], bfr[4];
#pragma unroll
    for (int i = 0; i < 4; ++i)
      af[i] = *(const bf16x8*)&As[(wm + i * 16 + fm) * LDT + fk8];
#pragma unroll
    for (int j = 0; j < 4; ++j)
      bfr[j] = *(const bf16x8*)&Bs[(wn + j * 16 + fm) * LDT + fk8];
#pragma unroll
    for (int i = 0; i < 4; ++i)
#pragma unroll
      for (int j = 0; j < 4; ++j)
        acc[i][j] = __builtin_amdgcn_mfma_f32_16x16x32_bf16(af[i], bfr[j], acc[i][j], 0, 0, 0);
    __syncthreads();
  }

  // epilogue: C/D layout col=lane&15, row=quad*4+reg
#pragma unroll
  for (int j = 0; j < 4; ++j) {
    int col = bn * 128 + wn + j * 16 + fm;
    float bv = bias[col];
#pragma unroll
    for (int i = 0; i < 4; ++i) {
#pragma unroll
      for (int r = 0; r < 4; ++r) {
        int row = bm * 128 + wm + i * 16 + quad * 4 + r;
        float v = acc[i][j][r] + bv;
        C[(size_t)row * N + col] = (OutT)v;
      }
    }
  }
}

// ------------- flash attention: qh,kh,vh [B, L, H*DK] bf16 -> out same layout -------------
__global__ __launch_bounds__(256, 2) void attn_kernel(const bf16* __restrict__ qh,
                                                      const bf16* __restrict__ kh,
                                                      const bf16* __restrict__ vh,
                                                      bf16* __restrict__ out) {
  constexpr int LDK = 72;    // 64 + 8 pad
  constexpr int LDP = 72;    // half of kv (64) + 8 pad
  constexpr int LDV = 136;   // 128 + 8 pad
  __shared__ __align__(16) bf16 Ks[128 * LDK];   // K tile [kv 128][dk 64]
  __shared__ __align__(16) bf16 Ps[128 * LDP];   // P half-tile [q 128][kv 64]
  __shared__ __align__(16) bf16 Vts[64 * LDV];   // V^T tile [dk 64][kv 128]

  const int tid = threadIdx.x, lane = tid & 63, wave = tid >> 6;
  const int fm = lane & 15, quad = lane >> 4, fk8 = quad * 8;
  const int qt = blockIdx.x, h = blockIdx.y, b = blockIdx.z;
  const int q0 = qt * 128;
  const float scale = 0.125f;  // 1/sqrt(64)

  // Q fragments straight from global (rows 16B-contiguous along dk)
  const bf16* qbase = qh + ((size_t)b * LQ + q0) * DM + h * DK;
  bf16x8 qf[2][2];
#pragma unroll
  for (int i = 0; i < 2; ++i)
#pragma unroll
    for (int kk = 0; kk < 2; ++kk)
      qf[i][kk] = *(const bf16x8*)&qbase[(size_t)(wave * 32 + i * 16 + fm) * DM + kk * 32 + fk8];

  float row_m[2][4], row_l[2][4];
  f32x4 o_acc[2][4];
#pragma unroll
  for (int i = 0; i < 2; ++i)
#pragma unroll
    for (int r = 0; r < 4; ++r) { row_m[i][r] = -1e30f; row_l[i][r] = 0.f; }
#pragma unroll
  for (int i = 0; i < 2; ++i)
#pragma unroll
    for (int jd = 0; jd < 4; ++jd) {
      f32x4 z = {0.f, 0.f, 0.f, 0.f};
      o_acc[i][jd] = z;
    }

  const bf16* kbase = kh + (size_t)b * LKV * DM + h * DK;
  const bf16* vbase = vh + (size_t)b * LKV * DM + h * DK;

  for (int t = 0; t < LKV / 128; ++t) {
    // stage K tile and V^T tile
    {
      const int r0 = tid >> 3, c0 = (tid & 7) * 8;
#pragma unroll
      for (int p = 0; p < 4; ++p) {
        int row = r0 + p * 32;  // kv row within tile
        const size_t g = (size_t)(t * 128 + row) * DM + c0;
        bf16x8 k8 = *(const bf16x8*)&kbase[g];
        *(bf16x8*)&Ks[row * LDK + c0] = k8;
        bf16x8 v8 = *(const bf16x8*)&vbase[g];
#pragma unroll
        for (int jj = 0; jj < 8; ++jj) Vts[(c0 + jj) * LDV + row] = v8[jj];
      }
    }
    __syncthreads();

    // S = Q K^T : per wave rows 32 (2 m-tiles), cols 128 (8 n-tiles)
    f32x4 s[2][8];
#pragma unroll
    for (int i = 0; i < 2; ++i)
#pragma unroll
      for (int j = 0; j < 8; ++j) {
        f32x4 z = {0.f, 0.f, 0.f, 0.f};
        s[i][j] = z;
      }
#pragma unroll
    for (int kk = 0; kk < 2; ++kk) {
#pragma unroll
      for (int j = 0; j < 8; ++j) {
        bf16x8 kf = *(const bf16x8*)&Ks[(j * 16 + fm) * LDK + kk * 32 + fk8];
#pragma unroll
        for (int i = 0; i < 2; ++i)
          s[i][j] = __builtin_amdgcn_mfma_f32_16x16x32_bf16(qf[i][kk], kf, s[i][j], 0, 0, 0);
      }
    }

    // online softmax per row (row = quad*4 + r); row data spread over the 16 lanes of a quad
#pragma unroll
    for (int i = 0; i < 2; ++i) {
#pragma unroll
      for (int r = 0; r < 4; ++r) {
        float mt = -1e30f;
#pragma unroll
        for (int j = 0; j < 8; ++j) {
          s[i][j][r] *= scale;
          mt = fmaxf(mt, s[i][j][r]);
        }
#pragma unroll
        for (int d = 1; d < 16; d <<= 1) mt = fmaxf(mt, __shfl_xor(mt, d, 64));
        float nm = fmaxf(row_m[i][r], mt);
        float alpha = __expf(row_m[i][r] - nm);
        row_m[i][r] = nm;
        float ps = 0.f;
#pragma unroll
        for (int j = 0; j < 8; ++j) {
          float pv = __expf(s[i][j][r] - nm);
          s[i][j][r] = pv;
          ps += pv;
        }
#pragma unroll
        for (int d = 1; d < 16; d <<= 1) ps += __shfl_xor(ps, d, 64);
        row_l[i][r] = row_l[i][r] * alpha + ps;
#pragma unroll
        for (int jd = 0; jd < 4; ++jd) o_acc[i][jd][r] *= alpha;
      }
    }

    // P @ V in two kv-halves (P round-trip through LDS: C-layout -> A-layout).
    // Each wave touches only its own 32 P-rows => no cross-wave sync needed here.
#pragma unroll
    for (int half = 0; half < 2; ++half) {
#pragma unroll
      for (int i = 0; i < 2; ++i)
#pragma unroll
        for (int jl = 0; jl < 4; ++jl) {
          int j = half * 4 + jl;
#pragma unroll
          for (int r = 0; r < 4; ++r)
            Ps[(wave * 32 + i * 16 + quad * 4 + r) * LDP + jl * 16 + fm] = (bf16)s[i][j][r];
        }
#pragma unroll
      for (int ks = 0; ks < 2; ++ks) {
        int ksg = half * 2 + ks;
#pragma unroll
        for (int i = 0; i < 2; ++i) {
          bf16x8 pf = *(const bf16x8*)&Ps[(wave * 32 + i * 16 + fm) * LDP + ks * 32 + fk8];
#pragma unroll
          for (int jd = 0; jd < 4; ++jd) {
            bf16x8 vf = *(const bf16x8*)&Vts[(jd * 16 + fm) * LDV + ksg * 32 + fk8];
            o_acc[i][jd] = __builtin_amdgcn_mfma_f32_16x16x32_bf16(pf, vf, o_acc[i][jd], 0, 0, 0);
          }
        }
      }
    }
    __syncthreads();  // protect Ks/Vts (and Ps) before next tile's staging
  }

  // normalize and store (concat layout [B, LQ, H*DK])
  bf16* obase = out + ((size_t)b * LQ + q0) * DM + h * DK;
#pragma unroll
  for (int i = 0; i < 2; ++i) {
#pragma unroll
    for (int r = 0; r < 4; ++r) {
      float inv = 1.0f / row_l[i][r];
      int row = wave * 32 + i * 16 + quad * 4 + r;
#pragma unroll
      for (int jd = 0; jd < 4; ++jd)
        obase[(size_t)row * DM + jd * 16 + fm] = (bf16)(o_acc[i][jd][r] * inv);
    }
  }
}

extern "C" void kernel_launch(void* const* d_in, const int* in_sizes, int n_in,
                              void* d_out, int out_size, void* d_ws, size_t ws_size,
                              hipStream_t stream) {
  const float* q  = (const float*)d_in[0];
  const float* k  = (const float*)d_in[1];
  const float* v  = (const float*)d_in[2];
  const float* Wq = (const float*)d_in[3];
  const float* bq = (const float*)d_in[4];
  const float* Wk = (const float*)d_in[5];
  const float* bk = (const float*)d_in[6];
  const float* Wv = (const float*)d_in[7];
  const float* bv = (const float*)d_in[8];
  const float* Wo = (const float*)d_in[9];
  const float* bo = (const float*)d_in[10];
  float* out = (float*)d_out;

  char* ws = (char*)d_ws;
  size_t off = 0;
  auto alloc = [&](size_t bytes) -> void* {
    void* p = ws + off;
    off += (bytes + 255) & ~(size_t)255;
    return p;
  };

  const size_t nq = (size_t)BB * LQ * DM;     // 16.7M
  const size_t nk = (size_t)BB * LKV * DIMG;  // 4.2M
  const size_t nqh = (size_t)BB * LQ * DM;
  const size_t nkh = (size_t)BB * LKV * DM;

  bf16* qbf = (bf16*)alloc(nq * 2);      // reused as attn_out after qh is computed
  bf16* kbf = (bf16*)alloc(nk * 2);
  bf16* vbf = (bf16*)alloc(nk * 2);
  bf16* WqT = (bf16*)alloc((size_t)DM * DM * 2);
  bf16* WkT = (bf16*)alloc((size_t)DM * DIMG * 2);
  bf16* WvT = (bf16*)alloc((size_t)DM * DIMG * 2);
  bf16* WoT = (bf16*)alloc((size_t)DM * DM * 2);
  bf16* qh  = (bf16*)alloc(nqh * 2);
  bf16* kh  = (bf16*)alloc(nkh * 2);
  bf16* vh  = (bf16*)alloc(nkh * 2);
  bf16* attn_out = qbf;  // alias: qbf dead after the Q projection

  // converts
  cvt_f32_bf16<<<(int)(nq / 4 / 256), 256, 0, stream>>>(q, qbf, (int)(nq / 4));
  cvt_f32_bf16<<<(int)(nk / 4 / 256), 256, 0, stream>>>(k, kbf, (int)(nk / 4));
  cvt_f32_bf16<<<(int)(nk / 4 / 256), 256, 0, stream>>>(v, vbf, (int)(nk / 4));

  // weight transposes: W[K,N] -> WT[N,K]
  transpose_w<<<dim3(DM / 64, DM / 64), 256, 0, stream>>>(Wq, WqT, DM, DM);
  transpose_w<<<dim3(DIMG / 64, DM / 64), 256, 0, stream>>>(Wk, WkT, DIMG, DM);
  transpose_w<<<dim3(DIMG / 64, DM / 64), 256, 0, stream>>>(Wv, WvT, DIMG, DM);
  transpose_w<<<dim3(DM / 64, DM / 64), 256, 0, stream>>>(Wo, WoT, DM, DM);

  // projections
  gemm_bt<bf16><<<dim3(BB * LQ / 128, DM / 128), 256, 0, stream>>>(qbf, WqT, bq, qh,
                                                                   BB * LQ, DM, DM);
  gemm_bt<bf16><<<dim3(BB * LKV / 128, DM / 128), 256, 0, stream>>>(kbf, WkT, bk, kh,
                                                                    BB * LKV, DM, DIMG);
  gemm_bt<bf16><<<dim3(BB * LKV / 128, DM / 128), 256, 0, stream>>>(vbf, WvT, bv, vh,
                                                                    BB * LKV, DM, DIMG);

  // attention
  attn_kernel<<<dim3(LQ / 128, H, BB), 256, 0, stream>>>(qh, kh, vh, attn_out);

  // output projection (fp32 out)
  gemm_bt<float><<<dim3(BB * LQ / 128, DM / 128), 256, 0, stream>>>(attn_out, WoT, bo, out,
                                                                    BB * LQ, DM, DM);
}